// Round 5
// baseline (269.698 us; speedup 1.0000x reference)
//
#include <hip/hip_runtime.h>

#define HH  512
#define WW  512
#define RAD 10
#define KK  21
#define SEG 8                   // output rows per block
#define NROWS (SEG + 2 * RAD)   // 28 raw rows per block
#define NSEG (HH / SEG)         // 64 segments per image
#define LSTRIDE 540             // LDS row stride (floats): 532 used; 16B-aligned,
                                // mod 32 = 28 -> b128 start banks uniform

// Fused separable Gaussian blur (21x21, sigma=3), reflect padding.
// SEG=8 -> LDS 17.3KB -> 8 blocks/CU = 32 waves/CU (occupancy-first design:
// rounds 3-4 proved the compiler re-serializes per-wave load batches, so
// latency must be hidden by wave count, not per-wave MLP).
// XCD swizzle: 8-XCD round-robin dispatch assumed; each XCD gets 12 whole
// images, segments contiguous -> vertical halo re-reads hit the local L2.
__global__ __launch_bounds__(256, 8) void gauss_blur_kernel(
    const float* __restrict__ x, float* __restrict__ out, int n_img)
{
    // g[d] = exp(-d^2/18), w = g/sum(g); 2D kernel = outer(w,w) exactly.
    const float wt[KK] = {
        0.00051432f, 0.00147793f, 0.00380033f, 0.00874446f, 0.01800488f,
        0.03317359f, 0.05469399f, 0.08069227f, 0.10652936f, 0.12584957f,
        0.13303907f,
        0.12584957f, 0.10652936f, 0.08069227f, 0.05469399f, 0.03317359f,
        0.01800488f, 0.00874446f, 0.00380033f, 0.00147793f, 0.00051432f
    };

    __shared__ __align__(16) float vbuf[SEG * LSTRIDE];   // 17.28 KB

    // ---- block -> (img, seg) with XCD-locality swizzle ----
    const int lin = blockIdx.x;
    int img, seg;
    if ((n_img & 7) == 0) {
        const int per_xcd = n_img >> 3;        // images per XCD (12)
        const int xcd = lin & 7;               // dispatch round-robin by lin%8
        const int i   = lin >> 3;              // sequence within this XCD
        img = xcd * per_xcd + (i / NSEG);
        seg = i % NSEG;                        // contiguous segs on one XCD
    } else {
        img = lin / NSEG;
        seg = lin % NSEG;
    }

    const int t  = threadIdx.x;
    const int c0 = 2 * t;          // phase-1 columns: c0, c0+1
    const int c1 = c0 + 1;
    const int y0 = seg * SEG;

    const float* xim = x   + (size_t)img * (HH * WW);
    float*       oim = out + (size_t)img * (HH * WW);

    // ---------------- Phase 1: vertical blur -> LDS ----------------
    float2 rows[NROWS];
    #pragma unroll
    for (int i = 0; i < NROWS; ++i) {
        int r  = y0 - RAD + i;
        int rr = r < 0 ? -r : (r > HH - 1 ? 2 * (HH - 1) - r : r);
        rows[i] = *(const float2*)(xim + rr * WW + c0);
    }

    #pragma unroll
    for (int r = 0; r < SEG; ++r) {
        float vx = 0.f, vy = 0.f;
        #pragma unroll
        for (int k = 0; k < KK; ++k) {
            vx = fmaf(wt[k], rows[r + k].x, vx);
            vy = fmaf(wt[k], rows[r + k].y, vy);
        }
        float* vb = vbuf + r * LSTRIDE;
        *(float2*)(vb + RAD + c0) = make_float2(vx, vy);
        // reflect pads in x
        if (c0 >= 1 && c0 <= RAD)           vb[RAD - c0] = vx;
        if (c1 <= RAD)                      vb[RAD - c1] = vy;
        if (c0 >= WW - 11 && c0 <= WW - 2)  vb[RAD + 2 * (WW - 1) - c0] = vx;
        if (c1 >= WW - 11 && c1 <= WW - 2)  vb[RAD + 2 * (WW - 1) - c1] = vy;
    }

    __syncthreads();   // the only barrier

    // ---------------- Phase 2: horizontal blur ----------------
    // 256 tasks, one per thread: r = t & 7 (row), q = t >> 3 (16-col group)
    const int r = t & (SEG - 1);
    const int q = t >> 3;                        // 0..31
    const float* vr = vbuf + r * LSTRIDE + q * 16;   // 16B aligned

    float wnd[36];
    #pragma unroll
    for (int j = 0; j < 9; ++j) {
        float4 v4 = *(const float4*)(vr + 4 * j);
        wnd[4*j]   = v4.x; wnd[4*j+1] = v4.y;
        wnd[4*j+2] = v4.z; wnd[4*j+3] = v4.w;
    }

    float acc[16];
    #pragma unroll
    for (int j = 0; j < 16; ++j) {
        float s = 0.f;
        #pragma unroll
        for (int k = 0; k < KK; ++k)
            s = fmaf(wt[k], wnd[j + k], s);
        acc[j] = s;
    }

    float* op = oim + (size_t)(y0 + r) * WW + q * 16;
    #pragma unroll
    for (int j = 0; j < 4; ++j)
        *(float4*)(op + 4 * j) =
            make_float4(acc[4*j], acc[4*j+1], acc[4*j+2], acc[4*j+3]);
}

extern "C" void kernel_launch(void* const* d_in, const int* in_sizes, int n_in,
                              void* d_out, int out_size, void* d_ws, size_t ws_size,
                              hipStream_t stream) {
    const float* x = (const float*)d_in[0];
    float* out = (float*)d_out;
    const int n_img = in_sizes[0] / (HH * WW);     // 32*3 = 96
    dim3 grid(NSEG * n_img);                       // 6144 blocks
    gauss_blur_kernel<<<grid, dim3(256), 0, stream>>>(x, out, n_img);
}